// Round 22
// baseline (421.955 us; speedup 1.0000x reference)
//
#include <hip/hip_runtime.h>
#include <hip/hip_bf16.h>
#include <cstdint>
#include <cstddef>

#define S_ 256
#define N_ 1024
#define H_ 512
#define AD_ 128
static constexpr int M_TOTAL = N_ * S_;

typedef __attribute__((ext_vector_type(8))) short short8;
typedef __attribute__((ext_vector_type(4))) float f32x4;

// raw barrier WITHOUT the __syncthreads vmcnt(0) drain: LDS visibility only.
#define LDS_BARRIER()                                       \
  asm volatile("s_waitcnt lgkmcnt(0)" ::: "memory");        \
  __builtin_amdgcn_s_barrier()

// 16-lane (DPP-row) sum via VALU-only rotation reduce (no LDS-pipe traffic).
__device__ __forceinline__ float red16_dpp(float v) {
  union fi { float f; int i; };
  fi a, r;
  a.f = v;
  r.i = __builtin_amdgcn_update_dpp(0, a.i, 0xB1, 0xF, 0xF, true);   // quad xor1
  a.f += r.f;
  r.i = __builtin_amdgcn_update_dpp(0, a.i, 0x4E, 0xF, 0xF, true);   // quad xor2
  a.f += r.f;
  r.i = __builtin_amdgcn_update_dpp(0, a.i, 0x124, 0xF, 0xF, true);  // row_ror:4
  a.f += r.f;
  r.i = __builtin_amdgcn_update_dpp(0, a.i, 0x128, 0xF, 0xF, true);  // row_ror:8
  a.f += r.f;
  return a.f;
}

// ---------------------------------------------------------------------------
// K0: W1 [H][AD] f32 -> MFMA-fragment-ordered bf16 (B-frag = linear 16B/lane).
// ---------------------------------------------------------------------------
__global__ __launch_bounds__(256) void k_w1frag(
    const float* __restrict__ w1_pre, const float* __restrict__ w1_fol,
    unsigned short* __restrict__ w1f) {
  int idx = blockIdx.x * 256 + threadIdx.x;  // 0..65535
  int st = blockIdx.y;
  const float* w1 = st ? w1_fol : w1_pre;
  int j = idx & 7;
  int lane = (idx >> 3) & 63;
  int c = (idx >> 9) & 7;
  int kk = idx >> 12;
  int k = kk * 32 + ((lane >> 4) << 3) + j;
  int d = c * 16 + (lane & 15);
  __hip_bfloat16 hb = __float2bfloat16(w1[(size_t)k * AD_ + d]);
  w1f[(size_t)st * 65536 + idx] = *(unsigned short*)&hb;
}

// ---------------------------------------------------------------------------
// K1: inclusive prefix sum of is_valid -> pos (rank-1), per stream.
// ---------------------------------------------------------------------------
__global__ __launch_bounds__(1024) void k_scan(
    const int* __restrict__ valid_pre, const int* __restrict__ valid_fol,
    int* __restrict__ pos) {
  const int st = blockIdx.x;
  const int* valid = st ? valid_fol : valid_pre;
  __shared__ int buf[1024];
  const int t = threadIdx.x;
  buf[t] = valid[t];
  __syncthreads();
  for (int off = 1; off < 1024; off <<= 1) {
    int v = (t >= off) ? buf[t - off] : 0;
    __syncthreads();
    buf[t] += v;
    __syncthreads();
  }
  pos[st * N_ + t] = buf[t] - 1;
}

// ---------------------------------------------------------------------------
// K2: FUSED + CROSS-PAIR PIPELINED. Grid 256 (1 block/CU); block handles 8
// (st,n) pairs. Iteration j: phase1(pair j) 16-step streaming GEMM (round-21
// verified) INTERLEAVED with the PV of pair j-1 (ascending s, 16 s/step,
// reads the L3-resident tile fetched one pair ago; reuse distance ~136MB <
// 256MB Infinity Cache). vmcnt ordering: PV (L3) loads issued BEFORE the
// step's HBM prefetch + sched_barrier -> waiting on PV costs vmcnt(4) and
// the HBM stream never drains. Then tail-reduce, p3-reduce/part-write for
// pair j-1, softmax(pair j) -> wl. Iteration 8 = PV-only drain.
// ---------------------------------------------------------------------------
__global__ __launch_bounds__(512) void k_fused(
    const float* __restrict__ emb_pre, const float* __restrict__ emb_fol,
    const unsigned short* __restrict__ w1f,
    const float* __restrict__ w2_pre, const float* __restrict__ w2_fol,
    const unsigned char* __restrict__ mask_pre, const unsigned char* __restrict__ mask_fol,
    float* __restrict__ part) {
  __shared__ __align__(16) unsigned char As[32768];   // 2 buf x 16 rows x 1KB
  __shared__ float partb[2][8][16][2];                // 4 KB
  __shared__ float lgbuf[S_][2];                      // 2 KB
  __shared__ float wl[S_];                            // 1 KB
  __shared__ __align__(16) float p3[4][128][4];       // 8 KB

  const int b = blockIdx.x;             // 0..255
  const int t = threadIdx.x;
  const int w = t >> 6, lane = t & 63;
  const int r16 = lane & 15, kq = lane >> 4;
  const size_t SSTR = (size_t)N_ * H_;

  // phase-1 staging geometry (round-21 verified)
  unsigned wadr[4];
#pragma unroll
  for (int j = 0; j < 4; ++j) {
    int cb = (j & 1) * 1024 + lane * 16;
    int R  = (j >> 1) * 8 + w;
    int g16 = cb >> 5, half = (cb >> 4) & 1;
    wadr[j] = (unsigned)(R * 1024 + ((g16 ^ (R & 7)) * 16) + half * 8);
  }
  // PV thread layout
  const int sg = t >> 7, tt = t & 127, c0b = tt * 4;

  float4 nxt[4];
  const float* baseA = emb_pre;         // set per pair

#define LD_STEP(MS)                                                          \
  {                                                                          \
    _Pragma("unroll")                                                        \
    for (int j = 0; j < 4; ++j)                                              \
      nxt[j] = *(const float4*)(baseA + (size_t)(MS) * 16 * SSTR +           \
                                (size_t)(j >> 1) * 8 * SSTR +                \
                                (j & 1) * 256 + lane * 4);                   \
  }
#define ST_STEP(BUFB)                                                        \
  {                                                                          \
    _Pragma("unroll")                                                        \
    for (int j = 0; j < 4; ++j) {                                            \
      union { unsigned long long u; __hip_bfloat162 h[2]; } p;               \
      p.h[0] = __float22bfloat162_rn(make_float2(nxt[j].x, nxt[j].y));       \
      p.h[1] = __float22bfloat162_rn(make_float2(nxt[j].z, nxt[j].w));       \
      *(unsigned long long*)&As[(BUFB) + wadr[j]] = p.u;                     \
    }                                                                        \
  }

  short8 B[16];
  float w2v0 = 0.f, w2v1 = 0.f;
  float4 accv = (float4){0.f, 0.f, 0.f, 0.f};
  const float* prevEmbN = emb_pre;      // prev pair's emb + n*H (set at j>=1)
  float* prevPart = part;               // prev pair's output row

  for (int jp = 0; jp < 9; ++jp) {
    const bool do_p1 = (jp < 8), do_pv = (jp > 0);
    const int st = (jp >> 2) & 1;
    const int n  = b + (jp & 3) * 256;
    const float* __restrict__ emb = st ? emb_fol : emb_pre;
    const unsigned char* __restrict__ mask = st ? mask_fol : mask_pre;
    const float* __restrict__ w2 = st ? w2_fol : w2_pre;

    if (do_p1) {
      baseA = emb + ((size_t)w * N_ + n) * H_;
      const unsigned short* bb =
          w1f + (size_t)st * 65536 + w * 512 + (size_t)lane * 8;
#pragma unroll
      for (int kk = 0; kk < 16; ++kk) B[kk] = *(const short8*)(bb + kk * 4096);
      w2v0 = w2[(w * 16 + r16) * 2 + 0];
      w2v1 = w2[(w * 16 + r16) * 2 + 1];
      LD_STEP(0);
      ST_STEP(0);
      LD_STEP(1);
    }
    LDS_BARRIER();

    for (int ss = 0; ss < 16; ++ss) {
      const int cur = ss & 1;
      const int nb  = cur ^ 1;
      const unsigned abase = (unsigned)(cur << 14);

      if (do_p1 && ss < 15) ST_STEP((unsigned)(nb << 14));

      // PV loads FIRST (older than HBM prefetch -> their wait = vmcnt(4))
      float4 xv0, xv1, xv2, xv3;
      if (do_pv) {
        const float* pb = prevEmbN + (size_t)(ss * 16 + sg * 4) * SSTR + c0b;
        xv0 = *(const float4*)(pb);
        xv1 = *(const float4*)(pb + SSTR);
        xv2 = *(const float4*)(pb + 2 * SSTR);
        xv3 = *(const float4*)(pb + 3 * SSTR);
      }
      __builtin_amdgcn_sched_barrier(0);  // keep HBM prefetch AFTER PV loads
      if (do_p1 && ss < 14) LD_STEP(ss + 2);

      if (do_p1 && ss > 0 && lane < 4) {  // deferred lgbuf reduce (step ss-1)
        int vv = w * 4 + lane;
        int row = vv >> 1, rr = vv & 1;
        float v = 0.f;
#pragma unroll
        for (int g = 0; g < 8; ++g) v += partb[nb][g][row][rr];
        lgbuf[(ss - 1) * 16 + row][rr] = v;
      }

      if (do_p1) {
        f32x4 a0 = (f32x4){0.f, 0.f, 0.f, 0.f};
        f32x4 a1 = (f32x4){0.f, 0.f, 0.f, 0.f};
#pragma unroll
        for (int kk = 0; kk < 16; ++kk) {
          const unsigned ra = abase +
              (unsigned)(r16 * 1024 + (((kk * 4 + kq) ^ (r16 & 7)) * 16));
          short8 a = *(const short8*)&As[ra];
          if (kk & 1)
            a1 = __builtin_amdgcn_mfma_f32_16x16x32_bf16(a, B[kk], a1, 0, 0, 0);
          else
            a0 = __builtin_amdgcn_mfma_f32_16x16x32_bf16(a, B[kk], a0, 0, 0, 0);
        }
#pragma unroll
        for (int q = 0; q < 4; ++q) {
          float xc = fminf(fmaxf(a0[q] + a1[q], -10.f), 10.f);
          float e  = __expf(2.f * xc);
          float th = (e - 1.f) / (e + 1.f);
          float p0 = red16_dpp(th * w2v0);
          float p1 = red16_dpp(th * w2v1);
          if (r16 == 0) {
            partb[cur][w][kq * 4 + q][0] = p0;
            partb[cur][w][kq * 4 + q][1] = p1;
          }
        }
      }

      if (do_pv) {  // PV accumulate (wl = prev pair's weights)
        const int s0v = ss * 16 + sg * 4;
        float w0 = wl[s0v], w1v = wl[s0v + 1], w2w = wl[s0v + 2], w3 = wl[s0v + 3];
        accv.x += w0 * xv0.x + w1v * xv1.x + w2w * xv2.x + w3 * xv3.x;
        accv.y += w0 * xv0.y + w1v * xv1.y + w2w * xv2.y + w3 * xv3.y;
        accv.z += w0 * xv0.z + w1v * xv1.z + w2w * xv2.z + w3 * xv3.z;
        accv.w += w0 * xv0.w + w1v * xv1.w + w2w * xv2.w + w3 * xv3.w;
      }
      LDS_BARRIER();
    }

    if (do_p1 && lane < 4) {  // tail lgbuf reduce (step 15, buf parity 1)
      int vv = w * 4 + lane;
      int row = vv >> 1, rr = vv & 1;
      float v = 0.f;
#pragma unroll
      for (int g = 0; g < 8; ++g) v += partb[1][g][row][rr];
      lgbuf[240 + row][rr] = v;
    }
    if (do_pv) *(float4*)&p3[sg][tt][0] = accv;
    LDS_BARRIER();

    if (do_pv && t < 128) {  // finalize PV of pair jp-1
      float4 r;
      r.x = p3[0][t][0] + p3[1][t][0] + p3[2][t][0] + p3[3][t][0];
      r.y = p3[0][t][1] + p3[1][t][1] + p3[2][t][1] + p3[3][t][1];
      r.z = p3[0][t][2] + p3[1][t][2] + p3[2][t][2] + p3[3][t][2];
      r.w = p3[0][t][3] + p3[1][t][3] + p3[2][t][3] + p3[3][t][3];
      *(float4*)&prevPart[t * 4] = r;
    }

    if (do_p1 && w == 0) {  // softmax(pair jp) -> wl
      uchar4 mkb = *(const uchar4*)(mask + (size_t)n * S_ + lane * 4);
      float l0[4], l1[4];
      bool mk[4];
#pragma unroll
      for (int i = 0; i < 4; ++i) {
        l0[i] = lgbuf[lane * 4 + i][0];
        l1[i] = lgbuf[lane * 4 + i][1];
      }
      mk[0] = mkb.x != 0; mk[1] = mkb.y != 0;
      mk[2] = mkb.z != 0; mk[3] = mkb.w != 0;
      float q0[4], q1[4];
#pragma unroll
      for (int r = 0; r < 2; ++r) {
        float* lv = r ? l1 : l0;
        float* qq = r ? q1 : q0;
        float m1 = fmaxf(fmaxf(lv[0], lv[1]), fmaxf(lv[2], lv[3]));
#pragma unroll
        for (int off = 32; off; off >>= 1) m1 = fmaxf(m1, __shfl_xor(m1, off));
        float e[4], s1 = 0.f;
#pragma unroll
        for (int i = 0; i < 4; ++i) { e[i] = __expf(lv[i] - m1); s1 += e[i]; }
#pragma unroll
        for (int off = 32; off; off >>= 1) s1 += __shfl_xor(s1, off);
        float inv1 = 1.f / s1;
        float v[4];
#pragma unroll
        for (int i = 0; i < 4; ++i) v[i] = mk[i] ? -INFINITY : e[i] * inv1;
        float m2 = fmaxf(fmaxf(v[0], v[1]), fmaxf(v[2], v[3]));
#pragma unroll
        for (int off = 32; off; off >>= 1) m2 = fmaxf(m2, __shfl_xor(m2, off));
        float e2[4], s2 = 0.f;
#pragma unroll
        for (int i = 0; i < 4; ++i) {
          e2[i] = mk[i] ? 0.f : __expf(v[i] - m2);
          s2 += e2[i];
        }
#pragma unroll
        for (int off = 32; off; off >>= 1) s2 += __shfl_xor(s2, off);
        float inv2 = 1.f / s2;
#pragma unroll
        for (int i = 0; i < 4; ++i) qq[i] = e2[i] * inv2;
      }
#pragma unroll
      for (int i = 0; i < 4; ++i) wl[lane * 4 + i] = 0.5f * (q0[i] + q1[i]);
    }
    LDS_BARRIER();

    // roll pipeline state
    prevEmbN = emb + (size_t)n * H_;
    prevPart = part + ((size_t)st * N_ + n) * H_;
    accv = (float4){0.f, 0.f, 0.f, 0.f};
  }
#undef LD_STEP
#undef ST_STEP
}

// ---------------------------------------------------------------------------
// K5: valid/pos gather -> out[n][st*512 + h].
// ---------------------------------------------------------------------------
__global__ __launch_bounds__(256) void k_combine(
    const float* __restrict__ part, const int* __restrict__ pos,
    const int* __restrict__ valid_pre, const int* __restrict__ valid_fol,
    float* __restrict__ out) {
  const int n = blockIdx.x, t = threadIdx.x;
  const int st = t >> 7;
  const int c = (t & 127) * 4;
  const int* valid = st ? valid_fol : valid_pre;
  float4 r = {0.f, 0.f, 0.f, 0.f};
  if (valid[n] > 0) {
    int np = pos[st * N_ + n]; if (np < 0) np = 0;
    r = *(const float4*)&part[((size_t)st * N_ + np) * H_ + c];
  }
  *(float4*)&out[(size_t)n * 1024 + st * 512 + c] = r;
}

// ---------------------------------------------------------------------------
extern "C" void kernel_launch(void* const* d_in, const int* in_sizes, int n_in,
                              void* d_out, int out_size, void* d_ws, size_t ws_size,
                              hipStream_t stream) {
  const float* emb_pre = (const float*)d_in[0];
  const float* emb_fol = (const float*)d_in[1];
  const unsigned char* mask_pre = (const unsigned char*)d_in[2];
  const unsigned char* mask_fol = (const unsigned char*)d_in[3];
  const int* valid_pre = (const int*)d_in[4];
  const int* valid_fol = (const int*)d_in[5];
  const float* w1_pre = (const float*)d_in[6];
  const float* w2_pre = (const float*)d_in[7];
  const float* w1_fol = (const float*)d_in[8];
  const float* w2_fol = (const float*)d_in[9];
  float* out = (float*)d_out;

  char* ws = (char*)d_ws;
  unsigned short* w1f = (unsigned short*)ws;                    // 256 KiB
  int*   pos    = (int*)(ws + 262144);                          // 8 KiB
  float* part   = (float*)(ws + 270336);                        // 4 MiB [2][N][H]

  hipLaunchKernelGGL(k_w1frag, dim3(256, 2), dim3(256), 0, stream,
                     w1_pre, w1_fol, w1f);
  hipLaunchKernelGGL(k_scan, dim3(2), dim3(1024), 0, stream,
                     valid_pre, valid_fol, pos);
  hipLaunchKernelGGL(k_fused, dim3(256), dim3(512), 0, stream,
                     emb_pre, emb_fol, w1f, w2_pre, w2_fol,
                     mask_pre, mask_fol, part);
  hipLaunchKernelGGL(k_combine, dim3(N_), dim3(256), 0, stream,
                     part, pos, valid_pre, valid_fol, out);
}

// Round 23
// 371.739 us; speedup vs baseline: 1.1351x; 1.1351x over previous
//
#include <hip/hip_runtime.h>
#include <hip/hip_bf16.h>
#include <cstdint>
#include <cstddef>

#define S_ 256
#define N_ 1024
#define H_ 512
#define AD_ 128
static constexpr int M_TOTAL = N_ * S_;   // 262144 rows per stream (m = s*N + n)

typedef __attribute__((ext_vector_type(8))) short short8;
typedef __attribute__((ext_vector_type(4))) float f32x4;

// raw barrier WITHOUT the __syncthreads vmcnt(0) drain: LDS visibility only.
#define LDS_BARRIER()                                       \
  asm volatile("s_waitcnt lgkmcnt(0)" ::: "memory");        \
  __builtin_amdgcn_s_barrier()

// 16-lane (DPP-row) sum via VALU-only rotation reduce (no LDS-pipe traffic).
__device__ __forceinline__ float red16_dpp(float v) {
  union fi { float f; int i; };
  fi a, r;
  a.f = v;
  r.i = __builtin_amdgcn_update_dpp(0, a.i, 0xB1, 0xF, 0xF, true);   // quad xor1
  a.f += r.f;
  r.i = __builtin_amdgcn_update_dpp(0, a.i, 0x4E, 0xF, 0xF, true);   // quad xor2
  a.f += r.f;
  r.i = __builtin_amdgcn_update_dpp(0, a.i, 0x124, 0xF, 0xF, true);  // row_ror:4
  a.f += r.f;
  r.i = __builtin_amdgcn_update_dpp(0, a.i, 0x128, 0xF, 0xF, true);  // row_ror:8
  a.f += r.f;
  return a.f;
}

// ---------------------------------------------------------------------------
// K0: W1 [H][AD] f32 -> MFMA-fragment-ordered bf16 (B-frag = linear 16B/lane).
// ---------------------------------------------------------------------------
__global__ __launch_bounds__(256) void k_w1frag(
    const float* __restrict__ w1_pre, const float* __restrict__ w1_fol,
    unsigned short* __restrict__ w1f) {
  int idx = blockIdx.x * 256 + threadIdx.x;  // 0..65535
  int st = blockIdx.y;
  const float* w1 = st ? w1_fol : w1_pre;
  int j = idx & 7;
  int lane = (idx >> 3) & 63;
  int c = (idx >> 9) & 7;
  int kk = idx >> 12;
  int k = kk * 32 + ((lane >> 4) << 3) + j;
  int d = c * 16 + (lane & 15);
  __hip_bfloat16 hb = __float2bfloat16(w1[(size_t)k * AD_ + d]);
  w1f[(size_t)st * 65536 + idx] = *(unsigned short*)&hb;
}

// ---------------------------------------------------------------------------
// K1: inclusive prefix sum of is_valid -> pos (rank-1), per stream.
// ---------------------------------------------------------------------------
__global__ __launch_bounds__(1024) void k_scan(
    const int* __restrict__ valid_pre, const int* __restrict__ valid_fol,
    int* __restrict__ pos) {
  const int st = blockIdx.x;
  const int* valid = st ? valid_fol : valid_pre;
  __shared__ int buf[1024];
  const int t = threadIdx.x;
  buf[t] = valid[t];
  __syncthreads();
  for (int off = 1; off < 1024; off <<= 1) {
    int v = (t >= off) ? buf[t - off] : 0;
    __syncthreads();
    buf[t] += v;
    __syncthreads();
  }
  pos[st * N_ + t] = buf[t] - 1;
}

// ---------------------------------------------------------------------------
// K2: logits GEMM, pv2-shaped streaming, TWO s-rows per step (64 steps,
// half the barriers). Per step: 2 dense 32KB regions (s, s+1) staged via
// nxt[8] regs 2 steps ahead -> XOR-swizzled dbuf LDS (2x32KB); 32 MFMA
// (dual-acc per s); tanh/@W2/DPP epilogue -> part (dbuf); deferred
// cross-wave reduce writes logits(step ss-1). One RAW barrier per step.
// ---------------------------------------------------------------------------
__global__ __launch_bounds__(512) void k_logits(
    const float* __restrict__ emb_pre, const float* __restrict__ emb_fol,
    const unsigned short* __restrict__ w1f,
    const float* __restrict__ w2_pre, const float* __restrict__ w2_fol,
    float* __restrict__ logits) {
  __shared__ __align__(16) unsigned char As[65536];   // 2 buf x 32 rows x 1KB
  __shared__ float part[2][8][2][16][2];              // [buf][wave][rg][n][r]

  const int bid = blockIdx.x;          // 0..255
  const int st  = bid >> 7;
  const int idx = bid & 127;
  const int nc  = idx >> 1;            // 0..63
  const int sh  = idx & 1;             // 0..1
  const int n0 = nc * 16, s0 = sh * 128;
  const float* __restrict__ emb = st ? emb_fol : emb_pre;
  const float* __restrict__ w2  = st ? w2_fol : w2_pre;

  const int t = threadIdx.x;
  const int w = t >> 6, lane = t & 63;
  const int r16 = lane & 15, kq = lane >> 4;

  // B: wave w's 16-col tile, all 16 K-chunks, register-resident (64 VGPR)
  short8 B[16];
  {
    const unsigned short* bb = w1f + (size_t)st * 65536 + w * 512 + (size_t)lane * 8;
#pragma unroll
    for (int kk = 0; kk < 16; ++kk) B[kk] = *(const short8*)(bb + kk * 4096);
  }
  const float w2v0 = w2[(w * 16 + r16) * 2 + 0];
  const float w2v1 = w2[(w * 16 + r16) * 2 + 1];

  // staging: thread (srow 0..31, sl 0..15): srow = s_local*16 + nrow.
  // Loads 8 float4 at float4-index sl + j*16 of its 2KB row.
  const int srow = t >> 4, sl = t & 15;
  const int s_local = srow >> 4, nrow = srow & 15;
  const size_t SSTR = (size_t)N_ * H_;
  const float* sbase = emb + ((size_t)(s0 + s_local) * N_ + n0 + nrow) * H_ + sl * 4;
  unsigned wadr[8];
#pragma unroll
  for (int j = 0; j < 8; ++j) {
    int g = j * 8 + (sl >> 1);                       // 16B granule 0..63
    wadr[j] = (unsigned)(srow * 1024 + ((g ^ (srow & 7)) * 16) + (sl & 1) * 8);
  }
  // deferred-reduce assignment: lanes 0..7, v = w*8+lane covers 64 outputs
  const int vv = w * 8 + lane;                        // valid when lane<8
  const int drg = vv >> 5, dn = (vv >> 1) & 15, drr = vv & 1;

  float4 nxt[8];
#pragma unroll
  for (int j = 0; j < 8; ++j) nxt[j] = *(const float4*)(sbase + j * 64);
  // prologue: write step 0 into As[0]
#pragma unroll
  for (int j = 0; j < 8; ++j) {
    union { unsigned long long u; __hip_bfloat162 h[2]; } p;
    p.h[0] = __float22bfloat162_rn(make_float2(nxt[j].x, nxt[j].y));
    p.h[1] = __float22bfloat162_rn(make_float2(nxt[j].z, nxt[j].w));
    *(unsigned long long*)&As[wadr[j]] = p.u;
  }
#pragma unroll
  for (int j = 0; j < 8; ++j) nxt[j] = *(const float4*)(sbase + 2 * SSTR + j * 64);
  LDS_BARRIER();

  for (int ss = 0; ss < 64; ++ss) {
    const int cur = ss & 1;
    const int nb  = cur ^ 1;
    const unsigned abase = (unsigned)(cur << 15);

    // write step ss+1 (regs loaded last iter) into the other buffer
    if (ss < 63) {
#pragma unroll
      for (int j = 0; j < 8; ++j) {
        union { unsigned long long u; __hip_bfloat162 h[2]; } p;
        p.h[0] = __float22bfloat162_rn(make_float2(nxt[j].x, nxt[j].y));
        p.h[1] = __float22bfloat162_rn(make_float2(nxt[j].z, nxt[j].w));
        *(unsigned long long*)&As[(nb << 15) + wadr[j]] = p.u;
      }
    }
    // issue loads for step ss+2 (survive across the raw barrier)
    if (ss < 62) {
      const float* nbp = sbase + (size_t)(2 * (ss + 2)) * SSTR;
#pragma unroll
      for (int j = 0; j < 8; ++j) nxt[j] = *(const float4*)(nbp + j * 64);
    }
    // deferred cross-wave reduce: logits for step ss-1 (part[nb])
    if (ss > 0 && lane < 8) {
      float v = 0.f;
#pragma unroll
      for (int g = 0; g < 8; ++g) v += part[nb][g][drg][dn][drr];
      int s_out = s0 + 2 * (ss - 1) + drg;
      logits[((size_t)st * M_TOTAL + (size_t)s_out * N_ + n0 + dn) * 2 + drr] = v;
    }

    // compute: 32 MFMAs (two s-subtiles, dual accumulators each)
    f32x4 a00 = (f32x4){0.f, 0.f, 0.f, 0.f}, a01 = a00, a10 = a00, a11 = a00;
#pragma unroll
    for (int kk = 0; kk < 16; ++kk) {
      const unsigned ra0 = abase +
          (unsigned)(r16 * 1024 + (((kk * 4 + kq) ^ (r16 & 7)) * 16));
      short8 f0 = *(const short8*)&As[ra0];
      short8 f1 = *(const short8*)&As[ra0 + 16384];
      if (kk & 1) {
        a01 = __builtin_amdgcn_mfma_f32_16x16x32_bf16(f0, B[kk], a01, 0, 0, 0);
        a11 = __builtin_amdgcn_mfma_f32_16x16x32_bf16(f1, B[kk], a11, 0, 0, 0);
      } else {
        a00 = __builtin_amdgcn_mfma_f32_16x16x32_bf16(f0, B[kk], a00, 0, 0, 0);
        a10 = __builtin_amdgcn_mfma_f32_16x16x32_bf16(f1, B[kk], a10, 0, 0, 0);
      }
    }

    // epilogue: tanh (exp-form), @W2, DPP reduce -> part[cur]
#pragma unroll
    for (int rg = 0; rg < 2; ++rg) {
#pragma unroll
      for (int q = 0; q < 4; ++q) {
        float av = rg ? (a10[q] + a11[q]) : (a00[q] + a01[q]);
        float xc = fminf(fmaxf(av, -10.f), 10.f);
        float e  = __expf(2.f * xc);
        float th = (e - 1.f) / (e + 1.f);
        float p0 = red16_dpp(th * w2v0);
        float p1 = red16_dpp(th * w2v1);
        if (r16 == 0) {
          part[cur][w][rg][kq * 4 + q][0] = p0;
          part[cur][w][rg][kq * 4 + q][1] = p1;
        }
      }
    }
    LDS_BARRIER();  // sole barrier: As[nb] + part[cur] handoff (lgkm only)
  }

  // tail: reduce step 63 (cur for ss=63 is 1)
  if (lane < 8) {
    float v = 0.f;
#pragma unroll
    for (int g = 0; g < 8; ++g) v += part[1][g][drg][dn][drr];
    int s_out = s0 + 126 + drg;
    logits[((size_t)st * M_TOTAL + (size_t)s_out * N_ + n0 + dn) * 2 + drr] = v;
  }
}

// ---------------------------------------------------------------------------
// K4: PV with FUSED double-softmax. Block = (st, 16-n chunk, s-half).
// Phase A: softmax over all S=256 for the block's 16 source-n rows straight
// from logits (32 threads/n, 8 s each, 32-lane shfl reductions) -> wl LDS.
// Phase B: pv2's proven streaming loop (32KB dense bursts, s descending).
// ---------------------------------------------------------------------------
__global__ __launch_bounds__(512) void k_pv2(
    const float* __restrict__ emb_pre, const float* __restrict__ emb_fol,
    const float* __restrict__ logits,
    const unsigned char* __restrict__ mask_pre, const unsigned char* __restrict__ mask_fol,
    float* __restrict__ part) {
  const int bid = blockIdx.x;          // 0..255
  const int st  = bid >> 7;
  const int idx = bid & 127;
  const int nc  = idx >> 1;            // 0..63
  const int sh  = idx & 1;             // 0..1
  const int n0 = nc * 16, s0 = sh * 128;
  const float* __restrict__ emb = st ? emb_fol : emb_pre;
  const unsigned char* __restrict__ mask = st ? mask_fol : mask_pre;

  const int t = threadIdx.x;
  __shared__ float wl[16][S_];         // 16 KB

  // ---- phase A: softmax for source rows n0..n0+15 over all 256 s
  {
    const int nn = t >> 5;             // 0..15
    const int g  = t & 31;             // 8 s-values per thread
    const int n  = n0 + nn;
    float l0[8], l1[8];
    bool mk[8];
#pragma unroll
    for (int i = 0; i < 8; ++i) {
      int s = g * 8 + i;
      float2 l = *(const float2*)&logits[((size_t)st * M_TOTAL + (size_t)s * N_ + n) * 2];
      l0[i] = l.x;
      l1[i] = l.y;
      mk[i] = mask[(size_t)n * S_ + s] != 0;
    }
    float q0[8], q1[8];
#pragma unroll
    for (int r = 0; r < 2; ++r) {
      float* lv = r ? l1 : l0;
      float* qq = r ? q1 : q0;
      float m1 = lv[0];
#pragma unroll
      for (int i = 1; i < 8; ++i) m1 = fmaxf(m1, lv[i]);
#pragma unroll
      for (int off = 16; off; off >>= 1) m1 = fmaxf(m1, __shfl_xor(m1, off));
      float e[8], s1 = 0.f;
#pragma unroll
      for (int i = 0; i < 8; ++i) { e[i] = __expf(lv[i] - m1); s1 += e[i]; }
#pragma unroll
      for (int off = 16; off; off >>= 1) s1 += __shfl_xor(s1, off);
      float inv1 = 1.f / s1;
      float v[8];
#pragma unroll
      for (int i = 0; i < 8; ++i) v[i] = mk[i] ? -INFINITY : e[i] * inv1;
      float m2 = v[0];
#pragma unroll
      for (int i = 1; i < 8; ++i) m2 = fmaxf(m2, v[i]);
#pragma unroll
      for (int off = 16; off; off >>= 1) m2 = fmaxf(m2, __shfl_xor(m2, off));
      float e2[8], s2 = 0.f;
#pragma unroll
      for (int i = 0; i < 8; ++i) {
        e2[i] = mk[i] ? 0.f : __expf(v[i] - m2);
        s2 += e2[i];
      }
#pragma unroll
      for (int off = 16; off; off >>= 1) s2 += __shfl_xor(s2, off);
      float inv2 = 1.f / s2;
#pragma unroll
      for (int i = 0; i < 8; ++i) qq[i] = e2[i] * inv2;
    }
#pragma unroll
    for (int i = 0; i < 8; ++i) wl[nn][g * 8 + i] = 0.5f * (q0[i] + q1[i]);
  }
  __syncthreads();

  // ---- phase B: PV streaming (verified pv2 loop)
  const int nl = t >> 5;               // 0..15 (n-row within chunk)
  const int c0 = (t & 31) * 4;         // h-base; acc j covers c0 + j*128

  float4 acc[4], cur[4], nxt[4];
#pragma unroll
  for (int j = 0; j < 4; ++j) acc[j] = (float4){0.f, 0.f, 0.f, 0.f};

  const float* rowp = emb + ((size_t)(s0 + 127) * N_ + n0 + nl) * H_ + c0;
  const size_t SSTR = (size_t)N_ * H_;
#pragma unroll
  for (int j = 0; j < 4; ++j) cur[j] = *(const float4*)(rowp + j * 128);

  for (int sl = 127; sl >= 0; --sl) {
    const float* nrow = rowp - SSTR;
    if (sl > 0) {
#pragma unroll
      for (int j = 0; j < 4; ++j) nxt[j] = *(const float4*)(nrow + j * 128);
    }
    const float wv = wl[nl][s0 + sl];
#pragma unroll
    for (int j = 0; j < 4; ++j) {
      acc[j].x += wv * cur[j].x;
      acc[j].y += wv * cur[j].y;
      acc[j].z += wv * cur[j].z;
      acc[j].w += wv * cur[j].w;
    }
#pragma unroll
    for (int j = 0; j < 4; ++j) cur[j] = nxt[j];
    rowp = nrow;
  }

  float* pp = part + (((size_t)(st * 2 + sh) * N_) + n0 + nl) * H_ + c0;
#pragma unroll
  for (int j = 0; j < 4; ++j) *(float4*)(pp + j * 128) = acc[j];
}

// ---------------------------------------------------------------------------
// K5: combine s-halves + valid/pos gather -> out[n][st*512 + h].
// ---------------------------------------------------------------------------
__global__ __launch_bounds__(256) void k_combine(
    const float* __restrict__ part, const int* __restrict__ pos,
    const int* __restrict__ valid_pre, const int* __restrict__ valid_fol,
    float* __restrict__ out) {
  const int n = blockIdx.x, t = threadIdx.x;
  const int st = t >> 7;
  const int c = (t & 127) * 4;
  const int* valid = st ? valid_fol : valid_pre;
  float4 r = {0.f, 0.f, 0.f, 0.f};
  if (valid[n] > 0) {
    int np = pos[st * N_ + n]; if (np < 0) np = 0;
    float4 a = *(const float4*)&part[(((size_t)(st * 2 + 0) * N_) + np) * H_ + c];
    float4 b = *(const float4*)&part[(((size_t)(st * 2 + 1) * N_) + np) * H_ + c];
    r.x = a.x + b.x; r.y = a.y + b.y; r.z = a.z + b.z; r.w = a.w + b.w;
  }
  *(float4*)&out[(size_t)n * 1024 + st * 512 + c] = r;
}

// ---------------------------------------------------------------------------
extern "C" void kernel_launch(void* const* d_in, const int* in_sizes, int n_in,
                              void* d_out, int out_size, void* d_ws, size_t ws_size,
                              hipStream_t stream) {
  const float* emb_pre = (const float*)d_in[0];
  const float* emb_fol = (const float*)d_in[1];
  const unsigned char* mask_pre = (const unsigned char*)d_in[2];
  const unsigned char* mask_fol = (const unsigned char*)d_in[3];
  const int* valid_pre = (const int*)d_in[4];
  const int* valid_fol = (const int*)d_in[5];
  const float* w1_pre = (const float*)d_in[6];
  const float* w2_pre = (const float*)d_in[7];
  const float* w1_fol = (const float*)d_in[8];
  const float* w2_fol = (const float*)d_in[9];
  float* out = (float*)d_out;

  char* ws = (char*)d_ws;
  unsigned short* w1f = (unsigned short*)ws;                    // 256 KiB
  int*   pos    = (int*)(ws + 262144);                          // 8 KiB
  float* logits = (float*)(ws + 270336);                        // 4 MiB  [2][S][N][2]
  float* part   = (float*)(ws + 270336 + 4194304);              // 8 MiB  [2][2][N][H]

  hipLaunchKernelGGL(k_w1frag, dim3(256, 2), dim3(256), 0, stream,
                     w1_pre, w1_fol, w1f);
  hipLaunchKernelGGL(k_scan, dim3(2), dim3(1024), 0, stream,
                     valid_pre, valid_fol, pos);
  hipLaunchKernelGGL(k_logits, dim3(256), dim3(512), 0, stream,
                     emb_pre, emb_fol, w1f, w2_pre, w2_fol, logits);
  hipLaunchKernelGGL(k_pv2, dim3(256), dim3(512), 0, stream,
                     emb_pre, emb_fol, logits, mask_pre, mask_fol, part);
  hipLaunchKernelGGL(k_combine, dim3(N_), dim3(256), 0, stream,
                     part, pos, valid_pre, valid_fol, out);
}